// Round 7
// baseline (282.709 us; speedup 1.0000x reference)
//
#include <hip/hip_runtime.h>
#include <math.h>

typedef _Float16 f16;
typedef f16 f16x8 __attribute__((ext_vector_type(8)));
typedef f16 f16x4 __attribute__((ext_vector_type(4)));
typedef float f32x4 __attribute__((ext_vector_type(4)));

#define H_   8
#define E_   512
#define DK   64
#define NPOS 1023

// async global->LDS, 16B per lane. LDS dest is WAVE-UNIFORM base; HW writes
// base + lane*16 (linear). Global src is per-lane. Both sides linear (rule #21).
#define GLL(SRC, DST) __builtin_amdgcn_global_load_lds( \
    (const __attribute__((address_space(1))) void*)(SRC), \
    (__attribute__((address_space(3))) void*)(DST), 16, 0, 0)

// ---------------- fp32 -> f16 conversion pre-pass (memory-bound) ----------------
struct CSeg { const float* src; f16* dst; int n4; };
struct CArgs { CSeg s[9]; };
__global__ __launch_bounds__(256) void conv_f16(CArgs a) {
    const int stride = gridDim.x * 256;
    const int gid = blockIdx.x * 256 + threadIdx.x;
    for (int si = 0; si < 9; ++si) {
        const float* __restrict__ src = a.s[si].src;
        f16* __restrict__ dst = a.s[si].dst;
        const int n4 = a.s[si].n4;
        for (int i = gid; i < n4; i += stride) {
            const float4 v = ((const float4*)src)[i];
            f16x4 h; h[0] = (f16)v.x; h[1] = (f16)v.y; h[2] = (f16)v.z; h[3] = (f16)v.w;
            ((f16x4*)dst)[i] = h;
        }
    }
}

// ---------------- f16 MFMA GEMM, m97 structure ----------------
// C = scale*(A(M,512) @ W(512,512)^T + bias (+bias2)). A,W f16 (pre-converted).
// 128x128 tile, BK=32, SINGLE-buffer LDS (16 KB), 4 waves (64x64 quadrant each):
// per k-step {barrier; 4x global_load_lds(16B); barrier(drain); 8x ds_read_b128;
// 16 MFMA}. TLP (4 blocks/CU) hides the drain (m114). Linear LDS both sides.
// modes: 0 fp32 row-major (M,512) | 1 f16 (B,H,DK,512) | 2 f16 (B,H,512,DK) | 3 f16 (B,H,NPOS,DK)
struct PArg {
    const f16* A; const f16* W; const float* bias; const float* bias2;
    void* C; int Mvalid; int mode; float scale;
};
struct PArgs { PArg g[4]; };

__device__ __forceinline__ void gemm128_body(const PArg g, int bx, int by) {
    __shared__ __align__(16) f16 Al[128 * 32];
    __shared__ __align__(16) f16 Wl[128 * 32];
    const int tid = threadIdx.x;
    const int lane = tid & 63, w = tid >> 6;
    const int quad = lane >> 4, l15 = lane & 15;
    const int wr = w >> 1, wc = w & 1;          // 2x2 wave grid, 64x64 each
    const int m0 = by * 128, n0 = bx * 128;

    // global_load_lds mapping: wave w, instr i in {0,1} fills LDS rows
    // [w*32+i*16, +16) (64 B/row). lane -> row w*32+i*16+(lane>>2), 16B chunk lane&3.
    const int r0 = w * 32 + (lane >> 2);
    const int c0 = (lane & 3) * 8;              // f16 elements
    int ar0 = m0 + r0;      if (ar0 >= g.Mvalid) ar0 = g.Mvalid - 1;   // pos tail clamp
    int ar1 = m0 + r0 + 16; if (ar1 >= g.Mvalid) ar1 = g.Mvalid - 1;
    const f16* A0 = g.A + (size_t)ar0 * 512 + c0;
    const f16* A1 = g.A + (size_t)ar1 * 512 + c0;
    const f16* W0 = g.W + (size_t)(n0 + r0) * 512 + c0;
    const f16* W1 = g.W + (size_t)(n0 + r0 + 16) * 512 + c0;
    f16* const lA0 = &Al[(w * 32) * 32];        // wave-uniform LDS bases
    f16* const lA1 = &Al[(w * 32 + 16) * 32];
    f16* const lW0 = &Wl[(w * 32) * 32];
    f16* const lW1 = &Wl[(w * 32 + 16) * 32];

    f32x4 acc[4][4];
    #pragma unroll
    for (int m = 0; m < 4; ++m)
        #pragma unroll
        for (int n = 0; n < 4; ++n) acc[m][n] = (f32x4){0.f, 0.f, 0.f, 0.f};

    for (int ki = 0; ki < 16; ++ki) {
        const int k0 = ki * 32;
        if (ki) __syncthreads();                // prev k-step's frag reads done
        GLL(A0 + k0, lA0);
        GLL(A1 + k0, lA1);
        GLL(W0 + k0, lW0);
        GLL(W1 + k0, lW1);
        __syncthreads();                        // drain: tiles resident in LDS

        f16x8 af[4], bf[4];
        #pragma unroll
        for (int m = 0; m < 4; ++m)
            af[m] = *(const f16x8*)&Al[(wr * 64 + m * 16 + l15) * 32 + quad * 8];
        #pragma unroll
        for (int n = 0; n < 4; ++n)
            bf[n] = *(const f16x8*)&Wl[(wc * 64 + n * 16 + l15) * 32 + quad * 8];
        #pragma unroll
        for (int m = 0; m < 4; ++m)
            #pragma unroll
            for (int n = 0; n < 4; ++n)
                acc[m][n] = __builtin_amdgcn_mfma_f32_16x16x32_f16(af[m], bf[n], acc[m][n], 0, 0, 0);
    }

    // C/D layout: col = lane&15, row = (lane>>4)*4 + reg
    const int mq = m0 + wr * 64 + quad * 4;
    const int nq = n0 + wc * 64 + l15;
    #pragma unroll
    for (int m = 0; m < 4; ++m) {
        #pragma unroll
        for (int n = 0; n < 4; ++n) {
            const int gr0 = mq + m * 16;
            const int col = nq + n * 16;
            float bs = g.bias ? g.bias[col] : 0.f;
            if (g.bias2) bs += g.bias2[col];
            const f32x4 a = acc[m][n];
            if (g.mode == 0) {
                float* C = (float*)g.C;
                #pragma unroll
                for (int r = 0; r < 4; ++r) C[(size_t)(gr0 + r) * 512 + col] = a[r] + bs;
            } else if (g.mode == 1) {
                f16* C = (f16*)g.C;
                const int b = gr0 >> 9, t = gr0 & 511;
                const int hh = col >> 6, dk = col & 63;
                f16x4 hv;
                #pragma unroll
                for (int r = 0; r < 4; ++r) hv[r] = (f16)((a[r] + bs) * g.scale);
                *(f16x4*)&C[(((size_t)b * H_ + hh) * DK + dk) * 512 + t] = hv;
            } else if (g.mode == 2) {
                f16* C = (f16*)g.C;
                const int b = gr0 >> 9, t = gr0 & 511;
                const int hh = col >> 6, dk = col & 63;
                #pragma unroll
                for (int r = 0; r < 4; ++r)
                    C[(((size_t)b * H_ + hh) * 512 + t + r) * DK + dk] = (f16)((a[r] + bs) * g.scale);
            } else {
                f16* C = (f16*)g.C;
                const int hh = col >> 6, dk = col & 63;
                #pragma unroll
                for (int r = 0; r < 4; ++r) {
                    const int gm = gr0 + r;
                    if (gm < g.Mvalid) {
                        const int b = gm / NPOS, t = gm - b * NPOS;
                        C[(((size_t)b * H_ + hh) * NPOS + t) * DK + dk] = (f16)a[r];
                    }
                }
            }
        }
    }
}

// XCD-locality swizzle (T1): each XCD owns a contiguous range of logical tiles t;
// decode bx = t&3 so the 4 n-tiles sharing one 128-row A-panel run back-to-back on
// the same XCD. nwg % 8 == 0 for all groups -> bijective.
// fused: Q (256) | K (256) | V (256) | Pos (512)
__global__ __launch_bounds__(256, 4) void proj_all(PArgs a) {
    const int id = blockIdx.x;
    int gi, rem, nwg;
    if (id < 768) { gi = id >> 8; rem = id & 255; nwg = 256; }
    else          { gi = 3;       rem = id - 768; nwg = 512; }
    const int t = (rem & 7) * (nwg >> 3) + (rem >> 3);
    gemm128_body(a.g[gi], t & 3, t >> 2);
}
__global__ __launch_bounds__(256, 4) void proj_one(PArg g) {
    const int t = (blockIdx.x & 7) * 32 + (blockIdx.x >> 3);
    gemm128_body(g, t & 3, t >> 2);
}

// ---------------- MFMA flash attention with rel-shift via ds_permute ----------------
// Block = (64-row i-tile, h, b); 4 waves; wave w owns rows [w*16, w*16+16).
// Q fragments live in REGISTERS (loaded once; afV hoisted out of the j-loop).
// 1/sqrt(dk) pre-folded into Qh and dpbf by the projection -> no per-score mul.
// Register prefetch of next j-tile (K/V/P/mask) during compute; 3 barriers per j-tile.
// LDS: Ka 9216 (reused for W) + Va 9216 + Pa 18432 + Ma 4096 = 40960 B -> 4 blocks/CU.
// Grid is 1D (1024) with XCD swizzle: the 8 i-tile blocks sharing one (b,h)'s
// K/V/P panels run contiguously on one XCD.
__global__ __launch_bounds__(256, 4) void attn_mfma(
    const f16* __restrict__ Qh,   // (B,H,T1,DK) = 0.125*(q + bq + pbu)
    const f16* __restrict__ Kh,   // (B,H,T2,DK)
    const f16* __restrict__ Vt,   // (B,H,DK,T2)
    const f16* __restrict__ Ph,   // (B,H,NPOS,DK)
    const float* __restrict__ pbu, const float* __restrict__ pbv,
    const unsigned char* __restrict__ bmask,   // (B,T2)
    const unsigned char* __restrict__ cmask,   // (T1,T1)
    f16* __restrict__ CTX)        // (B,T1,E) f16
{
    __shared__ f16 Ka[64 * 72];             // K tile; W written into wave-own rows
    __shared__ f16 Va[64 * 72];             // V^T tile [d][j]
    __shared__ f16 Pa[128 * 72];            // P window [nw][d]
    __shared__ unsigned char Ma[64 * 64];   // combined mask tile [r][c]

    const int tid = threadIdx.x;
    const int lane = tid & 63, w = tid >> 6;
    const int quad = lane >> 4, l15 = lane & 15;
    const int id = blockIdx.x;
    const int lg = (id & 7) * 128 + (id >> 3);   // XCD swizzle: contiguous (b,h) per XCD
    const int it = lg & 7, bh = lg >> 3;
    const int h = bh & 7, b = bh >> 3;
    const int i0 = it * 64;
    const int rowt = w * 16 + quad * 4;     // tile-local row base of this lane
    const int sr = tid >> 3, sc = (tid & 7) * 8;   // staging row/col (8 lanes per 64-col row)
    const int mr = tid >> 2, mc = (tid & 3) * 16;  // mask staging

    // Q fragment in registers: lane reads its own row (w*16+l15), both k-halves.
    // afV = afQ + 0.125*(pbv-pbu) is loop-invariant -> hoisted.
    f16x8 afQ[2], afV[2];
    {
        const f16* qp = &Qh[((size_t)bh * 512 + i0 + w * 16 + l15) * 64 + quad * 8];
        afQ[0] = *(const f16x8*)qp;
        afQ[1] = *(const f16x8*)(qp + 32);
        #pragma unroll
        for (int ks = 0; ks < 2; ++ks) {
            f16x8 d;
            #pragma unroll
            for (int j = 0; j < 8; ++j) {
                const int dd = ks * 32 + quad * 8 + j;
                d[j] = (f16)(0.125f * (pbv[h * 64 + dd] - pbu[h * 64 + dd]));
            }
            afV[ks] = afQ[ks] + d;
        }
    }

    float m_run[4], l_run[4];
    f32x4 accO[4];
    #pragma unroll
    for (int x = 0; x < 4; ++x) {
        m_run[x] = -__builtin_inff(); l_run[x] = 0.f;
        accO[x] = (f32x4){0.f, 0.f, 0.f, 0.f};
    }

    // ---- explicit prefetch registers (NO arrays/lambdas: avoid scratch spill) ----
    uint4 pK0, pK1, pV0, pV1, pP0, pP1, pP2, pP3, pM;
    {
        const int j0 = 0, nbase = 448 - i0;
        pK0 = *(const uint4*)&Kh[((size_t)bh * 512 + j0 + sr) * 64 + sc];
        pK1 = *(const uint4*)&Kh[((size_t)bh * 512 + j0 + sr + 32) * 64 + sc];
        pV0 = *(const uint4*)&Vt[((size_t)bh * 64 + sr) * 512 + j0 + sc];
        pV1 = *(const uint4*)&Vt[((size_t)bh * 64 + sr + 32) * 512 + j0 + sc];
        int n0_ = nbase + sr;       if (n0_ > NPOS - 1) n0_ = NPOS - 1;
        int n1_ = nbase + sr + 32;  if (n1_ > NPOS - 1) n1_ = NPOS - 1;
        int n2_ = nbase + sr + 64;  if (n2_ > NPOS - 1) n2_ = NPOS - 1;
        int n3_ = nbase + sr + 96;  if (n3_ > NPOS - 1) n3_ = NPOS - 1;
        pP0 = *(const uint4*)&Ph[((size_t)bh * NPOS + n0_) * 64 + sc];
        pP1 = *(const uint4*)&Ph[((size_t)bh * NPOS + n1_) * 64 + sc];
        pP2 = *(const uint4*)&Ph[((size_t)bh * NPOS + n2_) * 64 + sc];
        pP3 = *(const uint4*)&Ph[((size_t)bh * NPOS + n3_) * 64 + sc];
        const uint4 cm = *(const uint4*)&cmask[(size_t)(i0 + mr) * 512 + j0 + mc];
        const uint4 bm = *(const uint4*)&bmask[(size_t)b * 512 + j0 + mc];
        pM.x = cm.x | bm.x; pM.y = cm.y | bm.y; pM.z = cm.z | bm.z; pM.w = cm.w | bm.w;
    }

    for (int jt = 0; jt < 8; ++jt) {
        __syncthreads();                              // A: prev tile's frag reads done
        *(uint4*)&Ka[sr * 72 + sc] = pK0;
        *(uint4*)&Ka[(sr + 32) * 72 + sc] = pK1;
        *(uint4*)&Va[sr * 72 + sc] = pV0;
        *(uint4*)&Va[(sr + 32) * 72 + sc] = pV1;
        *(uint4*)&Pa[sr * 72 + sc] = pP0;
        *(uint4*)&Pa[(sr + 32) * 72 + sc] = pP1;
        *(uint4*)&Pa[(sr + 64) * 72 + sc] = pP2;
        *(uint4*)&Pa[(sr + 96) * 72 + sc] = pP3;
        *(uint4*)&Ma[mr * 64 + mc] = pM;
        __syncthreads();                              // B: staging visible

        if (jt < 7) {                                 // prefetch next j-tile during compute
            const int j0n = (jt + 1) * 64;
            const int nbase = j0n - i0 + 448;
            pK0 = *(const uint4*)&Kh[((size_t)bh * 512 + j0n + sr) * 64 + sc];
            pK1 = *(const uint4*)&Kh[((size_t)bh * 512 + j0n + sr + 32) * 64 + sc];
            pV0 = *(const uint4*)&Vt[((size_t)bh * 64 + sr) * 512 + j0n + sc];
            pV1 = *(const uint4*)&Vt[((size_t)bh * 64 + sr + 32) * 512 + j0n + sc];
            int n0_ = nbase + sr;       if (n0_ > NPOS - 1) n0_ = NPOS - 1;
            int n1_ = nbase + sr + 32;  if (n1_ > NPOS - 1) n1_ = NPOS - 1;
            int n2_ = nbase + sr + 64;  if (n2_ > NPOS - 1) n2_ = NPOS - 1;
            int n3_ = nbase + sr + 96;  if (n3_ > NPOS - 1) n3_ = NPOS - 1;
            pP0 = *(const uint4*)&Ph[((size_t)bh * NPOS + n0_) * 64 + sc];
            pP1 = *(const uint4*)&Ph[((size_t)bh * NPOS + n1_) * 64 + sc];
            pP2 = *(const uint4*)&Ph[((size_t)bh * NPOS + n2_) * 64 + sc];
            pP3 = *(const uint4*)&Ph[((size_t)bh * NPOS + n3_) * 64 + sc];
            const uint4 cm = *(const uint4*)&cmask[(size_t)(i0 + mr) * 512 + j0n + mc];
            const uint4 bm = *(const uint4*)&bmask[(size_t)b * 512 + j0n + mc];
            pM.x = cm.x | bm.x; pM.y = cm.y | bm.y; pM.z = cm.z | bm.z; pM.w = cm.w | bm.w;
        }

        // AC: 4 blocks x 2 ks
        f32x4 accAC[4];
        #pragma unroll
        for (int nt = 0; nt < 4; ++nt) {
            accAC[nt] = (f32x4){0.f, 0.f, 0.f, 0.f};
            #pragma unroll
            for (int ks = 0; ks < 2; ++ks) {
                const f16x8 bf = *(const f16x8*)&Ka[(nt * 16 + l15) * 72 + ks * 32 + quad * 8];
                accAC[nt] = __builtin_amdgcn_mfma_f32_16x16x32_f16(afQ[ks], bf, accAC[nt], 0, 0, 0);
            }
        }
        // BD: wave-private 79-wide window -> 5 blocks (nw blocks 3-w .. 7-w)
        f32x4 accBD[5];
        #pragma unroll
        for (int u = 0; u < 5; ++u) {
            accBD[u] = (f32x4){0.f, 0.f, 0.f, 0.f};
            const int nts = (3 - w) + u;
            #pragma unroll
            for (int ks = 0; ks < 2; ++ks) {
                const f16x8 bf = *(const f16x8*)&Pa[(nts * 16 + l15) * 72 + ks * 32 + quad * 8];
                accBD[u] = __builtin_amdgcn_mfma_f32_16x16x32_f16(afV[ks], bf, accBD[u], 0, 0, 0);
            }
        }
        __syncthreads();                              // C: Ka/Pa frag reads done (W overwrites Ka)

        // gather (quad-local push permute) + mask + online softmax; W -> Ka wave-own rows
        #pragma unroll
        for (int rg = 0; rg < 4; ++rg) {
            const int qr = quad * 4 + rg;             // quad-local row 0..15
            const int rt = rowt + rg;                 // tile-local row
            float tmpv[5];
            #pragma unroll
            for (int u = 0; u < 5; ++u) {
                const int cl = l15 + (3 + u) * 16 + qr - 63;
                const int dst = (quad * 16 + (cl & 15)) << 2;
                tmpv[u] = __uint_as_float(
                    (unsigned)__builtin_amdgcn_ds_permute(dst, (int)__float_as_uint(accBD[u][rg])));
            }
            const bool hi = l15 > qr;                 // u = nt + (l15 > qr)
            float sv[4]; unsigned mk = 0;
            #pragma unroll
            for (int nt = 0; nt < 4; ++nt) {
                const int c = nt * 16 + l15;
                const float bdv = hi ? tmpv[nt + 1] : tmpv[nt];
                float s = accAC[nt][rg] + bdv;        // scale pre-folded into Qh/dpbf
                if (Ma[rt * 64 + c]) { s = -3.402823466e38f; mk |= 1u << nt; }
                sv[nt] = s;
            }
            float tmax = fmaxf(fmaxf(sv[0], sv[1]), fmaxf(sv[2], sv[3]));
            #pragma unroll
            for (int d = 1; d < 16; d <<= 1) tmax = fmaxf(tmax, __shfl_xor(tmax, d));
            const float mnew = fmaxf(m_run[rg], tmax);
            const float alpha = __expf(m_run[rg] - mnew);
            float rsum = 0.f;
            f16 wv[4];
            #pragma unroll
            for (int nt = 0; nt < 4; ++nt) {
                const float e = __expf(sv[nt] - mnew);
                rsum += e;                                      // denom over all j (ref semantics)
                wv[nt] = ((mk >> nt) & 1u) ? (f16)0.f : (f16)e; // zero masked for PV
            }
            #pragma unroll
            for (int d = 1; d < 16; d <<= 1) rsum += __shfl_xor(rsum, d);
            l_run[rg] = l_run[rg] * alpha + rsum;
            m_run[rg] = mnew;
            #pragma unroll
            for (int dt = 0; dt < 4; ++dt) accO[dt][rg] *= alpha;
            #pragma unroll
            for (int nt = 0; nt < 4; ++nt)
                Ka[rt * 72 + nt * 16 + l15] = wv[nt];
        }
        // PV: afW reads wave-own Ka rows (same-wave write -> lgkmcnt, no barrier)
        f16x8 afW[2];
        #pragma unroll
        for (int ks = 0; ks < 2; ++ks)
            afW[ks] = *(const f16x8*)&Ka[(w * 16 + l15) * 72 + ks * 32 + quad * 8];
        #pragma unroll
        for (int dt = 0; dt < 4; ++dt)
            #pragma unroll
            for (int ks = 0; ks < 2; ++ks) {
                const f16x8 bf = *(const f16x8*)&Va[(dt * 16 + l15) * 72 + ks * 32 + quad * 8];
                accO[dt] = __builtin_amdgcn_mfma_f32_16x16x32_f16(afW[ks], bf, accO[dt], 0, 0, 0);
            }
    }

    #pragma unroll
    for (int rg = 0; rg < 4; ++rg) {
        const float inv = 1.0f / l_run[rg];
        const int gi = i0 + rowt + rg;
        #pragma unroll
        for (int dt = 0; dt < 4; ++dt)
            CTX[((size_t)b * 512 + gi) * 512 + h * 64 + dt * 16 + l15] = (f16)(accO[dt][rg] * inv);
    }
}

extern "C" void kernel_launch(void* const* d_in, const int* in_sizes, int n_in,
                              void* d_out, int out_size, void* d_ws, size_t ws_size,
                              hipStream_t stream) {
    const float* query   = (const float*)d_in[0];
    const float* key     = (const float*)d_in[1];
    const float* value   = (const float*)d_in[2];
    const float* pos_enc = (const float*)d_in[3];
    const unsigned char* mask       = (const unsigned char*)d_in[4];
    const unsigned char* chunk_mask = (const unsigned char*)d_in[5];
    const float* Wq  = (const float*)d_in[6];
    const float* bq  = (const float*)d_in[7];
    const float* Wk  = (const float*)d_in[8];
    const float* bk  = (const float*)d_in[9];
    const float* Wv  = (const float*)d_in[10];
    const float* bv  = (const float*)d_in[11];
    const float* Wpos = (const float*)d_in[12];
    const float* Wo   = (const float*)d_in[13];
    const float* bo   = (const float*)d_in[14];
    const float* pbu  = (const float*)d_in[15];
    const float* pbv  = (const float*)d_in[16];
    float* out = (float*)d_out;

    f16* base = (f16*)d_ws;
    size_t off = 0;
    f16* ctx  = base + off; off += 4194304;   // (B,T1,E) attn output
    f16* Qhm  = base + off; off += 4194304;   // (B,H,T1,DK)  0.125*(q+bq+pbu)
    f16* Khm  = base + off; off += 4194304;   // (B,H,T2,DK)
    f16* Vtm  = base + off; off += 4194304;   // (B,H,DK,T2)
    f16* Phm  = base + off; off += 8380416;   // (B,H,NPOS,DK)
    f16* qf   = base + off; off += 4194304;   // f16 copies of fp32 inputs
    f16* kf   = base + off; off += 4194304;
    f16* vf   = base + off; off += 4194304;
    f16* pf   = base + off; off += 8380416;
    f16* wqf  = base + off; off += 262144;
    f16* wkf  = base + off; off += 262144;
    f16* wvf  = base + off; off += 262144;
    f16* wpf  = base + off; off += 262144;
    f16* wof  = base + off; off += 262144;

    CArgs ca;
    ca.s[0] = CSeg{pos_enc, pf,  2095104};
    ca.s[1] = CSeg{query,   qf,  1048576};
    ca.s[2] = CSeg{key,     kf,  1048576};
    ca.s[3] = CSeg{value,   vf,  1048576};
    ca.s[4] = CSeg{Wq,      wqf, 65536};
    ca.s[5] = CSeg{Wk,      wkf, 65536};
    ca.s[6] = CSeg{Wv,      wvf, 65536};
    ca.s[7] = CSeg{Wpos,    wpf, 65536};
    ca.s[8] = CSeg{Wo,      wof, 65536};
    conv_f16<<<dim3(2048), 256, 0, stream>>>(ca);

    PArgs pa;
    pa.g[0] = PArg{qf, wqf, bq, pbu,     (void*)Qhm, 8192,  2, 0.125f};
    pa.g[1] = PArg{kf, wkf, bk, nullptr, (void*)Khm, 8192,  2, 1.0f};
    pa.g[2] = PArg{vf, wvf, bv, nullptr, (void*)Vtm, 8192,  1, 1.0f};
    pa.g[3] = PArg{pf, wpf, nullptr, nullptr, (void*)Phm, 16368, 3, 1.0f};
    proj_all<<<dim3(1280), 256, 0, stream>>>(pa);

    attn_mfma<<<dim3(1024), 256, 0, stream>>>(Qhm, Khm, Vtm, Phm, pbu, pbv,
                                              mask, chunk_mask, ctx);

    PArg go = PArg{ctx, wof, bo, nullptr, (void*)out, 8192, 0, 1.0f};
    proj_one<<<dim3(256), 256, 0, stream>>>(go);
}

// Round 8
// 263.856 us; speedup vs baseline: 1.0715x; 1.0715x over previous
//
#include <hip/hip_runtime.h>
#include <math.h>

typedef _Float16 f16;
typedef f16 f16x8 __attribute__((ext_vector_type(8)));
typedef f16 f16x4 __attribute__((ext_vector_type(4)));
typedef float f32x4 __attribute__((ext_vector_type(4)));

#define H_   8
#define E_   512
#define DK   64
#define NPOS 1023

// async global->LDS, 16B per lane. LDS dest is WAVE-UNIFORM base; HW writes
// base + lane*16 (linear). Global src is per-lane. Both sides linear (rule #21).
#define GLL(SRC, DST) __builtin_amdgcn_global_load_lds( \
    (const __attribute__((address_space(1))) void*)(SRC), \
    (__attribute__((address_space(3))) void*)(DST), 16, 0, 0)

// ---------------- fp32 -> f16 conversion pre-pass (memory-bound) ----------------
struct CSeg { const float* src; f16* dst; int n4; };
struct CArgs { CSeg s[9]; };
__global__ __launch_bounds__(256) void conv_f16(CArgs a) {
    const int stride = gridDim.x * 256;
    const int gid = blockIdx.x * 256 + threadIdx.x;
    for (int si = 0; si < 9; ++si) {
        const float* __restrict__ src = a.s[si].src;
        f16* __restrict__ dst = a.s[si].dst;
        const int n4 = a.s[si].n4;
        for (int i = gid; i < n4; i += stride) {
            const float4 v = ((const float4*)src)[i];
            f16x4 h; h[0] = (f16)v.x; h[1] = (f16)v.y; h[2] = (f16)v.z; h[3] = (f16)v.w;
            ((f16x4*)dst)[i] = h;
        }
    }
}

// ---------------- f16 MFMA GEMM, m97 structure ----------------
// C = scale*(A(M,512) @ W(512,512)^T + bias (+bias2)). A,W f16 (pre-converted).
// 128x128 tile, BK=32, SINGLE-buffer LDS (16 KB), 4 waves (64x64 quadrant each):
// per k-step {barrier; 4x global_load_lds(16B); barrier(drain); 8x ds_read_b128;
// 16 MFMA}. TLP (4 blocks/CU) hides the drain (m114). Linear LDS both sides.
// modes: 0 fp32 row-major (M,512) | 1 f16 (B,H,DK,512) | 2 f16 (B,H,512,DK) | 3 f16 (B,H,NPOS,DK)
struct PArg {
    const f16* A; const f16* W; const float* bias; const float* bias2;
    void* C; int Mvalid; int mode; float scale;
};
struct PArgs { PArg g[4]; };

__device__ __forceinline__ void gemm128_body(const PArg g, int bx, int by) {
    __shared__ __align__(16) f16 Al[128 * 32];
    __shared__ __align__(16) f16 Wl[128 * 32];
    const int tid = threadIdx.x;
    const int lane = tid & 63, w = tid >> 6;
    const int quad = lane >> 4, l15 = lane & 15;
    const int wr = w >> 1, wc = w & 1;          // 2x2 wave grid, 64x64 each
    const int m0 = by * 128, n0 = bx * 128;

    // global_load_lds mapping: wave w, instr i in {0,1} fills LDS rows
    // [w*32+i*16, +16) (64 B/row). lane -> row w*32+i*16+(lane>>2), 16B chunk lane&3.
    const int r0 = w * 32 + (lane >> 2);
    const int c0 = (lane & 3) * 8;              // f16 elements
    int ar0 = m0 + r0;      if (ar0 >= g.Mvalid) ar0 = g.Mvalid - 1;   // pos tail clamp
    int ar1 = m0 + r0 + 16; if (ar1 >= g.Mvalid) ar1 = g.Mvalid - 1;
    const f16* A0 = g.A + (size_t)ar0 * 512 + c0;
    const f16* A1 = g.A + (size_t)ar1 * 512 + c0;
    const f16* W0 = g.W + (size_t)(n0 + r0) * 512 + c0;
    const f16* W1 = g.W + (size_t)(n0 + r0 + 16) * 512 + c0;
    f16* const lA0 = &Al[(w * 32) * 32];        // wave-uniform LDS bases
    f16* const lA1 = &Al[(w * 32 + 16) * 32];
    f16* const lW0 = &Wl[(w * 32) * 32];
    f16* const lW1 = &Wl[(w * 32 + 16) * 32];

    f32x4 acc[4][4];
    #pragma unroll
    for (int m = 0; m < 4; ++m)
        #pragma unroll
        for (int n = 0; n < 4; ++n) acc[m][n] = (f32x4){0.f, 0.f, 0.f, 0.f};

    for (int ki = 0; ki < 16; ++ki) {
        const int k0 = ki * 32;
        if (ki) __syncthreads();                // prev k-step's frag reads done
        GLL(A0 + k0, lA0);
        GLL(A1 + k0, lA1);
        GLL(W0 + k0, lW0);
        GLL(W1 + k0, lW1);
        __syncthreads();                        // drain: tiles resident in LDS

        f16x8 af[4], bf[4];
        #pragma unroll
        for (int m = 0; m < 4; ++m)
            af[m] = *(const f16x8*)&Al[(wr * 64 + m * 16 + l15) * 32 + quad * 8];
        #pragma unroll
        for (int n = 0; n < 4; ++n)
            bf[n] = *(const f16x8*)&Wl[(wc * 64 + n * 16 + l15) * 32 + quad * 8];
        #pragma unroll
        for (int m = 0; m < 4; ++m)
            #pragma unroll
            for (int n = 0; n < 4; ++n)
                acc[m][n] = __builtin_amdgcn_mfma_f32_16x16x32_f16(af[m], bf[n], acc[m][n], 0, 0, 0);
    }

    // C/D layout: col = lane&15, row = (lane>>4)*4 + reg
    const int mq = m0 + wr * 64 + quad * 4;
    const int nq = n0 + wc * 64 + l15;
    #pragma unroll
    for (int m = 0; m < 4; ++m) {
        #pragma unroll
        for (int n = 0; n < 4; ++n) {
            const int gr0 = mq + m * 16;
            const int col = nq + n * 16;
            float bs = g.bias ? g.bias[col] : 0.f;
            if (g.bias2) bs += g.bias2[col];
            const f32x4 a = acc[m][n];
            if (g.mode == 0) {
                float* C = (float*)g.C;
                #pragma unroll
                for (int r = 0; r < 4; ++r) C[(size_t)(gr0 + r) * 512 + col] = a[r] + bs;
            } else if (g.mode == 1) {
                f16* C = (f16*)g.C;
                const int b = gr0 >> 9, t = gr0 & 511;
                const int hh = col >> 6, dk = col & 63;
                f16x4 hv;
                #pragma unroll
                for (int r = 0; r < 4; ++r) hv[r] = (f16)((a[r] + bs) * g.scale);
                *(f16x4*)&C[(((size_t)b * H_ + hh) * DK + dk) * 512 + t] = hv;
            } else if (g.mode == 2) {
                f16* C = (f16*)g.C;
                const int b = gr0 >> 9, t = gr0 & 511;
                const int hh = col >> 6, dk = col & 63;
                #pragma unroll
                for (int r = 0; r < 4; ++r)
                    C[(((size_t)b * H_ + hh) * 512 + t + r) * DK + dk] = (f16)((a[r] + bs) * g.scale);
            } else {
                f16* C = (f16*)g.C;
                const int hh = col >> 6, dk = col & 63;
                #pragma unroll
                for (int r = 0; r < 4; ++r) {
                    const int gm = gr0 + r;
                    if (gm < g.Mvalid) {
                        const int b = gm / NPOS, t = gm - b * NPOS;
                        C[(((size_t)b * H_ + hh) * NPOS + t) * DK + dk] = (f16)a[r];
                    }
                }
            }
        }
    }
}

// XCD-locality swizzle (T1): each XCD owns a contiguous range of logical tiles t;
// decode bx = t&3 so the 4 n-tiles sharing one 128-row A-panel run back-to-back on
// the same XCD. nwg % 8 == 0 for all groups -> bijective.
// fused: Q (256) | K (256) | V (256) | Pos (512)
__global__ __launch_bounds__(256, 4) void proj_all(PArgs a) {
    const int id = blockIdx.x;
    int gi, rem, nwg;
    if (id < 768) { gi = id >> 8; rem = id & 255; nwg = 256; }
    else          { gi = 3;       rem = id - 768; nwg = 512; }
    const int t = (rem & 7) * (nwg >> 3) + (rem >> 3);
    gemm128_body(a.g[gi], t & 3, t >> 2);
}
__global__ __launch_bounds__(256, 4) void proj_one(PArg g) {
    const int t = (blockIdx.x & 7) * 32 + (blockIdx.x >> 3);
    gemm128_body(g, t & 3, t >> 2);
}

// ---------------- MFMA flash attention with rel-shift via ds_permute ----------------
// Block = (64-row i-tile, h, b); 4 waves; wave w owns rows [w*16, w*16+16).
// Q fragments in REGISTERS (afV hoisted); 1/sqrt(dk) pre-folded into Qh/dpbf.
// W has its OWN LDS buffer (Wa): softmax writes + PV reads are same-wave rows only
// -> NO barrier between MFMA phase and softmax/PV (2 barriers per j-tile).
// LDS: Ka 9216 + Va 9216 + Pa 18432 + Wa 9216 + Ma 4096 = 50176 B -> 3 blocks/CU.
// 3 blocks/CU keeps the per-XCD co-resident set <= 12 (b,h) panel sets (~3.4 MB),
// which FITS the 4 MB XCD L2 (R7's 4 blocks/CU -> 16 sets -> thrash, FETCH x6).
__global__ __launch_bounds__(256, 3) void attn_mfma(
    const f16* __restrict__ Qh,   // (B,H,T1,DK) = 0.125*(q + bq + pbu)
    const f16* __restrict__ Kh,   // (B,H,T2,DK)
    const f16* __restrict__ Vt,   // (B,H,DK,T2)
    const f16* __restrict__ Ph,   // (B,H,NPOS,DK)
    const float* __restrict__ pbu, const float* __restrict__ pbv,
    const unsigned char* __restrict__ bmask,   // (B,T2)
    const unsigned char* __restrict__ cmask,   // (T1,T1)
    f16* __restrict__ CTX)        // (B,T1,E) f16
{
    __shared__ f16 Ka[64 * 72];             // K tile
    __shared__ f16 Va[64 * 72];             // V^T tile [d][j]
    __shared__ f16 Pa[128 * 72];            // P window [nw][d]
    __shared__ f16 Wa[64 * 72];             // softmax weights (wave-own rows)
    __shared__ unsigned char Ma[64 * 64];   // combined mask tile [r][c]

    const int tid = threadIdx.x;
    const int lane = tid & 63, w = tid >> 6;
    const int quad = lane >> 4, l15 = lane & 15;
    const int id = blockIdx.x;
    const int lg = (id & 7) * 128 + (id >> 3);   // XCD swizzle: contiguous (b,h) per XCD
    const int it = lg & 7, bh = lg >> 3;
    const int h = bh & 7, b = bh >> 3;
    const int i0 = it * 64;
    const int rowt = w * 16 + quad * 4;     // tile-local row base of this lane
    const int sr = tid >> 3, sc = (tid & 7) * 8;   // staging row/col (8 lanes per 64-col row)
    const int mr = tid >> 2, mc = (tid & 3) * 16;  // mask staging

    // Q fragment in registers: lane reads its own row (w*16+l15), both k-halves.
    // afV = afQ + 0.125*(pbv-pbu) is loop-invariant -> hoisted.
    f16x8 afQ[2], afV[2];
    {
        const f16* qp = &Qh[((size_t)bh * 512 + i0 + w * 16 + l15) * 64 + quad * 8];
        afQ[0] = *(const f16x8*)qp;
        afQ[1] = *(const f16x8*)(qp + 32);
        #pragma unroll
        for (int ks = 0; ks < 2; ++ks) {
            f16x8 d;
            #pragma unroll
            for (int j = 0; j < 8; ++j) {
                const int dd = ks * 32 + quad * 8 + j;
                d[j] = (f16)(0.125f * (pbv[h * 64 + dd] - pbu[h * 64 + dd]));
            }
            afV[ks] = afQ[ks] + d;
        }
    }

    float m_run[4], l_run[4];
    f32x4 accO[4];
    #pragma unroll
    for (int x = 0; x < 4; ++x) {
        m_run[x] = -__builtin_inff(); l_run[x] = 0.f;
        accO[x] = (f32x4){0.f, 0.f, 0.f, 0.f};
    }

    // ---- explicit prefetch registers (NO arrays/lambdas: avoid scratch spill) ----
    uint4 pK0, pK1, pV0, pV1, pP0, pP1, pP2, pP3, pM;
    {
        const int j0 = 0, nbase = 448 - i0;
        pK0 = *(const uint4*)&Kh[((size_t)bh * 512 + j0 + sr) * 64 + sc];
        pK1 = *(const uint4*)&Kh[((size_t)bh * 512 + j0 + sr + 32) * 64 + sc];
        pV0 = *(const uint4*)&Vt[((size_t)bh * 64 + sr) * 512 + j0 + sc];
        pV1 = *(const uint4*)&Vt[((size_t)bh * 64 + sr + 32) * 512 + j0 + sc];
        int n0_ = nbase + sr;       if (n0_ > NPOS - 1) n0_ = NPOS - 1;
        int n1_ = nbase + sr + 32;  if (n1_ > NPOS - 1) n1_ = NPOS - 1;
        int n2_ = nbase + sr + 64;  if (n2_ > NPOS - 1) n2_ = NPOS - 1;
        int n3_ = nbase + sr + 96;  if (n3_ > NPOS - 1) n3_ = NPOS - 1;
        pP0 = *(const uint4*)&Ph[((size_t)bh * NPOS + n0_) * 64 + sc];
        pP1 = *(const uint4*)&Ph[((size_t)bh * NPOS + n1_) * 64 + sc];
        pP2 = *(const uint4*)&Ph[((size_t)bh * NPOS + n2_) * 64 + sc];
        pP3 = *(const uint4*)&Ph[((size_t)bh * NPOS + n3_) * 64 + sc];
        const uint4 cm = *(const uint4*)&cmask[(size_t)(i0 + mr) * 512 + j0 + mc];
        const uint4 bm = *(const uint4*)&bmask[(size_t)b * 512 + j0 + mc];
        pM.x = cm.x | bm.x; pM.y = cm.y | bm.y; pM.z = cm.z | bm.z; pM.w = cm.w | bm.w;
    }

    for (int jt = 0; jt < 8; ++jt) {
        __syncthreads();                              // A: prev tile's frag reads done
        *(uint4*)&Ka[sr * 72 + sc] = pK0;
        *(uint4*)&Ka[(sr + 32) * 72 + sc] = pK1;
        *(uint4*)&Va[sr * 72 + sc] = pV0;
        *(uint4*)&Va[(sr + 32) * 72 + sc] = pV1;
        *(uint4*)&Pa[sr * 72 + sc] = pP0;
        *(uint4*)&Pa[(sr + 32) * 72 + sc] = pP1;
        *(uint4*)&Pa[(sr + 64) * 72 + sc] = pP2;
        *(uint4*)&Pa[(sr + 96) * 72 + sc] = pP3;
        *(uint4*)&Ma[mr * 64 + mc] = pM;
        __syncthreads();                              // B: staging visible

        if (jt < 7) {                                 // prefetch next j-tile during compute
            const int j0n = (jt + 1) * 64;
            const int nbase = j0n - i0 + 448;
            pK0 = *(const uint4*)&Kh[((size_t)bh * 512 + j0n + sr) * 64 + sc];
            pK1 = *(const uint4*)&Kh[((size_t)bh * 512 + j0n + sr + 32) * 64 + sc];
            pV0 = *(const uint4*)&Vt[((size_t)bh * 64 + sr) * 512 + j0n + sc];
            pV1 = *(const uint4*)&Vt[((size_t)bh * 64 + sr + 32) * 512 + j0n + sc];
            int n0_ = nbase + sr;       if (n0_ > NPOS - 1) n0_ = NPOS - 1;
            int n1_ = nbase + sr + 32;  if (n1_ > NPOS - 1) n1_ = NPOS - 1;
            int n2_ = nbase + sr + 64;  if (n2_ > NPOS - 1) n2_ = NPOS - 1;
            int n3_ = nbase + sr + 96;  if (n3_ > NPOS - 1) n3_ = NPOS - 1;
            pP0 = *(const uint4*)&Ph[((size_t)bh * NPOS + n0_) * 64 + sc];
            pP1 = *(const uint4*)&Ph[((size_t)bh * NPOS + n1_) * 64 + sc];
            pP2 = *(const uint4*)&Ph[((size_t)bh * NPOS + n2_) * 64 + sc];
            pP3 = *(const uint4*)&Ph[((size_t)bh * NPOS + n3_) * 64 + sc];
            const uint4 cm = *(const uint4*)&cmask[(size_t)(i0 + mr) * 512 + j0n + mc];
            const uint4 bm = *(const uint4*)&bmask[(size_t)b * 512 + j0n + mc];
            pM.x = cm.x | bm.x; pM.y = cm.y | bm.y; pM.z = cm.z | bm.z; pM.w = cm.w | bm.w;
        }

        // AC: 4 blocks x 2 ks
        f32x4 accAC[4];
        #pragma unroll
        for (int nt = 0; nt < 4; ++nt) {
            accAC[nt] = (f32x4){0.f, 0.f, 0.f, 0.f};
            #pragma unroll
            for (int ks = 0; ks < 2; ++ks) {
                const f16x8 bf = *(const f16x8*)&Ka[(nt * 16 + l15) * 72 + ks * 32 + quad * 8];
                accAC[nt] = __builtin_amdgcn_mfma_f32_16x16x32_f16(afQ[ks], bf, accAC[nt], 0, 0, 0);
            }
        }
        // BD: wave-private 79-wide window -> 5 blocks (nw blocks 3-w .. 7-w)
        f32x4 accBD[5];
        #pragma unroll
        for (int u = 0; u < 5; ++u) {
            accBD[u] = (f32x4){0.f, 0.f, 0.f, 0.f};
            const int nts = (3 - w) + u;
            #pragma unroll
            for (int ks = 0; ks < 2; ++ks) {
                const f16x8 bf = *(const f16x8*)&Pa[(nts * 16 + l15) * 72 + ks * 32 + quad * 8];
                accBD[u] = __builtin_amdgcn_mfma_f32_16x16x32_f16(afV[ks], bf, accBD[u], 0, 0, 0);
            }
        }
        // NO barrier here: softmax writes go to Wa (wave-own rows), not Ka.

        // gather (quad-local push permute) + mask + online softmax; W -> Wa wave-own rows
        #pragma unroll
        for (int rg = 0; rg < 4; ++rg) {
            const int qr = quad * 4 + rg;             // quad-local row 0..15
            const int rt = rowt + rg;                 // tile-local row
            float tmpv[5];
            #pragma unroll
            for (int u = 0; u < 5; ++u) {
                const int cl = l15 + (3 + u) * 16 + qr - 63;
                const int dst = (quad * 16 + (cl & 15)) << 2;
                tmpv[u] = __uint_as_float(
                    (unsigned)__builtin_amdgcn_ds_permute(dst, (int)__float_as_uint(accBD[u][rg])));
            }
            const bool hi = l15 > qr;                 // u = nt + (l15 > qr)
            float sv[4]; unsigned mk = 0;
            #pragma unroll
            for (int nt = 0; nt < 4; ++nt) {
                const int c = nt * 16 + l15;
                const float bdv = hi ? tmpv[nt + 1] : tmpv[nt];
                float s = accAC[nt][rg] + bdv;        // scale pre-folded into Qh/dpbf
                if (Ma[rt * 64 + c]) { s = -3.402823466e38f; mk |= 1u << nt; }
                sv[nt] = s;
            }
            float tmax = fmaxf(fmaxf(sv[0], sv[1]), fmaxf(sv[2], sv[3]));
            #pragma unroll
            for (int d = 1; d < 16; d <<= 1) tmax = fmaxf(tmax, __shfl_xor(tmax, d));
            const float mnew = fmaxf(m_run[rg], tmax);
            const float alpha = __expf(m_run[rg] - mnew);
            float rsum = 0.f;
            f16 wv[4];
            #pragma unroll
            for (int nt = 0; nt < 4; ++nt) {
                const float e = __expf(sv[nt] - mnew);
                rsum += e;                                      // denom over all j (ref semantics)
                wv[nt] = ((mk >> nt) & 1u) ? (f16)0.f : (f16)e; // zero masked for PV
            }
            #pragma unroll
            for (int d = 1; d < 16; d <<= 1) rsum += __shfl_xor(rsum, d);
            l_run[rg] = l_run[rg] * alpha + rsum;
            m_run[rg] = mnew;
            #pragma unroll
            for (int dt = 0; dt < 4; ++dt) accO[dt][rg] *= alpha;
            #pragma unroll
            for (int nt = 0; nt < 4; ++nt)
                Wa[rt * 72 + nt * 16 + l15] = wv[nt];
        }
        // PV: afW reads wave-own Wa rows (same-wave write -> lgkmcnt, no barrier)
        f16x8 afW[2];
        #pragma unroll
        for (int ks = 0; ks < 2; ++ks)
            afW[ks] = *(const f16x8*)&Wa[(w * 16 + l15) * 72 + ks * 32 + quad * 8];
        #pragma unroll
        for (int dt = 0; dt < 4; ++dt)
            #pragma unroll
            for (int ks = 0; ks < 2; ++ks) {
                const f16x8 bf = *(const f16x8*)&Va[(dt * 16 + l15) * 72 + ks * 32 + quad * 8];
                accO[dt] = __builtin_amdgcn_mfma_f32_16x16x32_f16(afW[ks], bf, accO[dt], 0, 0, 0);
            }
    }

    #pragma unroll
    for (int rg = 0; rg < 4; ++rg) {
        const float inv = 1.0f / l_run[rg];
        const int gi = i0 + rowt + rg;
        #pragma unroll
        for (int dt = 0; dt < 4; ++dt)
            CTX[((size_t)b * 512 + gi) * 512 + h * 64 + dt * 16 + l15] = (f16)(accO[dt][rg] * inv);
    }
}

extern "C" void kernel_launch(void* const* d_in, const int* in_sizes, int n_in,
                              void* d_out, int out_size, void* d_ws, size_t ws_size,
                              hipStream_t stream) {
    const float* query   = (const float*)d_in[0];
    const float* key     = (const float*)d_in[1];
    const float* value   = (const float*)d_in[2];
    const float* pos_enc = (const float*)d_in[3];
    const unsigned char* mask       = (const unsigned char*)d_in[4];
    const unsigned char* chunk_mask = (const unsigned char*)d_in[5];
    const float* Wq  = (const float*)d_in[6];
    const float* bq  = (const float*)d_in[7];
    const float* Wk  = (const float*)d_in[8];
    const float* bk  = (const float*)d_in[9];
    const float* Wv  = (const float*)d_in[10];
    const float* bv  = (const float*)d_in[11];
    const float* Wpos = (const float*)d_in[12];
    const float* Wo   = (const float*)d_in[13];
    const float* bo   = (const float*)d_in[14];
    const float* pbu  = (const float*)d_in[15];
    const float* pbv  = (const float*)d_in[16];
    float* out = (float*)d_out;

    f16* base = (f16*)d_ws;
    size_t off = 0;
    f16* ctx  = base + off; off += 4194304;   // (B,T1,E) attn output
    f16* Qhm  = base + off; off += 4194304;   // (B,H,T1,DK)  0.125*(q+bq+pbu)
    f16* Khm  = base + off; off += 4194304;   // (B,H,T2,DK)
    f16* Vtm  = base + off; off += 4194304;   // (B,H,DK,T2)
    f16* Phm  = base + off; off += 8380416;   // (B,H,NPOS,DK)
    f16* qf   = base + off; off += 4194304;   // f16 copies of fp32 inputs
    f16* kf   = base + off; off += 4194304;
    f16* vf   = base + off; off += 4194304;
    f16* pf   = base + off; off += 8380416;
    f16* wqf  = base + off; off += 262144;
    f16* wkf  = base + off; off += 262144;
    f16* wvf  = base + off; off += 262144;
    f16* wpf  = base + off; off += 262144;
    f16* wof  = base + off; off += 262144;

    CArgs ca;
    ca.s[0] = CSeg{pos_enc, pf,  2095104};
    ca.s[1] = CSeg{query,   qf,  1048576};
    ca.s[2] = CSeg{key,     kf,  1048576};
    ca.s[3] = CSeg{value,   vf,  1048576};
    ca.s[4] = CSeg{Wq,      wqf, 65536};
    ca.s[5] = CSeg{Wk,      wkf, 65536};
    ca.s[6] = CSeg{Wv,      wvf, 65536};
    ca.s[7] = CSeg{Wpos,    wpf, 65536};
    ca.s[8] = CSeg{Wo,      wof, 65536};
    conv_f16<<<dim3(2048), 256, 0, stream>>>(ca);

    PArgs pa;
    pa.g[0] = PArg{qf, wqf, bq, pbu,     (void*)Qhm, 8192,  2, 0.125f};
    pa.g[1] = PArg{kf, wkf, bk, nullptr, (void*)Khm, 8192,  2, 1.0f};
    pa.g[2] = PArg{vf, wvf, bv, nullptr, (void*)Vtm, 8192,  1, 1.0f};
    pa.g[3] = PArg{pf, wpf, nullptr, nullptr, (void*)Phm, 16368, 3, 1.0f};
    proj_all<<<dim3(1280), 256, 0, stream>>>(pa);

    attn_mfma<<<dim3(1024), 256, 0, stream>>>(Qhm, Khm, Vtm, Phm, pbu, pbv,
                                              mask, chunk_mask, ctx);

    PArg go = PArg{ctx, wof, bo, nullptr, (void*)out, 8192, 0, 1.0f};
    proj_one<<<dim3(256), 256, 0, stream>>>(go);
}